// Round 1
// baseline (28.058 us; speedup 1.0000x reference)
//
#include <hip/hip_runtime.h>
#include <hip/hip_bf16.h>

#define HD 64
#define LSEQ 2048
#define NBATCH 1024
#define NSLOTS 8

// ---------------- Kernel 1: per-token tables ----------------
// Blocks 0..63: token v = blockIdx.x -> h_table[v], qi_table[v], sk_table[v], score[v]
// Block 64: transpose qr_w -> qr_wT ; Block 65: transpose out_w -> out_wT
__global__ __launch_bounds__(128) void build_tables_kernel(
    const float* __restrict__ embed, const float* __restrict__ w1, const float* __restrict__ b1,
    const float* __restrict__ w2, const float* __restrict__ b2,
    const float* __restrict__ gamma, const float* __restrict__ beta,
    const float* __restrict__ gate_w, const float* __restrict__ gate_b,
    const float* __restrict__ qi_w, const float* __restrict__ qi_b,
    const float* __restrict__ sk_w, const float* __restrict__ sk_b,
    const float* __restrict__ qr_w, const float* __restrict__ out_w,
    float* __restrict__ h_table, float* __restrict__ qi_table, float* __restrict__ sk_table,
    float* __restrict__ qr_wT, float* __restrict__ out_wT, float* __restrict__ score)
{
    const int blk = blockIdx.x;
    const int tid = threadIdx.x;

    if (blk >= 64) {
        // transposes: dst[c][r] = src[r][c]
        const float* src = (blk == 64) ? qr_w : out_w;
        float*       dst = (blk == 64) ? qr_wT : out_wT;
        for (int i = tid; i < HD * HD; i += 128) {
            int r = i >> 6, c = i & 63;
            dst[c * HD + r] = src[i];
        }
        return;
    }

    const int v = blk;
    __shared__ float E[HD];
    __shared__ float T1[2 * HD];
    __shared__ float Hrow[HD];

    if (tid < HD) E[tid] = embed[v * HD + tid];
    __syncthreads();

    // t1[j] = relu(b1[j] + sum_k E[k]*w1[j][k]), j = tid in [0,128)
    {
        float t1 = b1[tid];
        const float* w1r = w1 + tid * HD;
        #pragma unroll 8
        for (int k = 0; k < HD; ++k) t1 = fmaf(E[k], w1r[k], t1);
        T1[tid] = fmaxf(t1, 0.0f);
    }
    __syncthreads();

    // x[i] = E[i] + b2[i] + sum_j T1[j]*w2[i][j]; then LayerNorm across i (wave 0 only)
    if (tid < HD) {
        float x = E[tid] + b2[tid];
        const float* w2r = w2 + tid * 2 * HD;
        #pragma unroll 8
        for (int j = 0; j < 2 * HD; ++j) x = fmaf(T1[j], w2r[j], x);

        float mu = x;
        #pragma unroll
        for (int off = 1; off < 64; off <<= 1) mu += __shfl_xor(mu, off);
        mu *= (1.0f / 64.0f);
        float d = x - mu;
        float var = d * d;
        #pragma unroll
        for (int off = 1; off < 64; off <<= 1) var += __shfl_xor(var, off);
        var *= (1.0f / 64.0f);
        float h = d * rsqrtf(var + 1e-5f) * gamma[tid] + beta[tid];
        Hrow[tid] = h;
        h_table[v * HD + tid] = h;

        float sc = h * gate_w[tid];
        #pragma unroll
        for (int off = 1; off < 64; off <<= 1) sc += __shfl_xor(sc, off);
        if (tid == 0) score[v] = sc + gate_b[0];
    }
    __syncthreads();

    // qi row (wave 0) and sk row (wave 1)
    {
        const int i = tid & 63;
        const float* W  = (tid < HD) ? qi_w : sk_w;
        const float* Bv = (tid < HD) ? qi_b : sk_b;
        float acc = Bv[i];
        const float* Wr = W + i * HD;
        #pragma unroll 8
        for (int k = 0; k < HD; ++k) acc = fmaf(Hrow[k], Wr[k], acc);
        float* dst = (tid < HD) ? qi_table : sk_table;
        dst[v * HD + i] = acc;
    }
}

// ---------------- Kernel 2: rank-sort tokens by score desc ----------------
__global__ __launch_bounds__(64) void sort_tokens_kernel(const float* __restrict__ score,
                                                         int* __restrict__ order)
{
    const int t = threadIdx.x; // 0..63
    const float st = score[t];
    int rank = 0;
    for (int u = 0; u < 64; ++u) {
        float su = score[u];
        if (su > st || (su == st && u < t)) rank++;
    }
    order[rank] = t;
}

// ---------------- Kernel 3: per-batch-row main ----------------
__global__ __launch_bounds__(64) void main_kernel(
    const int* __restrict__ seq,
    const float* __restrict__ h_table, const float* __restrict__ qi_table,
    const float* __restrict__ sk_table, const float* __restrict__ qr_wT,
    const float* __restrict__ qr_b, const float* __restrict__ out_wT,
    const float* __restrict__ out_b, const int* __restrict__ order,
    float* __restrict__ out)
{
    const int b    = blockIdx.x;
    const int lane = threadIdx.x; // 0..63

    __shared__ int   hist[64];
    __shared__ int   slot_tok[NSLOTS];
    __shared__ float rbuf[64];

    hist[lane] = 0;
    __syncthreads();

    const int*  srow  = seq + (size_t)b * LSEQ;
    const int4* srow4 = (const int4*)srow;
    #pragma unroll
    for (int it = 0; it < LSEQ / 64 / 4; ++it) {
        int4 t4 = srow4[lane + it * 64];
        atomicAdd(&hist[t4.x], 1);
        atomicAdd(&hist[t4.y], 1);
        atomicAdd(&hist[t4.z], 1);
        atomicAdd(&hist[t4.w], 1);
    }
    __syncthreads();

    if (lane == 0) {
        int rem = NSLOTS, pos = 0;
        for (int t = 0; t < 64 && rem > 0; ++t) {
            int tok = order[t];
            int m = hist[tok];
            if (m > rem) m = rem;
            for (int i = 0; i < m; ++i) slot_tok[pos++] = tok;
            rem -= m;
        }
    }
    __syncthreads();

    int st[NSLOTS];
    #pragma unroll
    for (int s = 0; s < NSLOTS; ++s) st[s] = slot_tok[s];

    const int last = srow[LSEQ - 1];
    const float qk = qi_table[last * HD + lane];

    float mrow[NSLOTS], skrow[NSLOTS];
    #pragma unroll
    for (int s = 0; s < NSLOTS; ++s) {
        mrow[s]  = h_table[st[s] * HD + lane];
        skrow[s] = sk_table[st[s] * HD + lane];
    }

    const float scale = 0.125f; // 1/sqrt(64)

    // ---- Stage 1: r_attn = softmax(slot_keys . q_init * scale) ----
    float p[NSLOTS];
    #pragma unroll
    for (int s = 0; s < NSLOTS; ++s) p[s] = skrow[s] * qk;
    #pragma unroll
    for (int off = 1; off < 64; off <<= 1) {
        #pragma unroll
        for (int s = 0; s < NSLOTS; ++s) p[s] += __shfl_xor(p[s], off);
    }
    {
        float mx = p[0];
        #pragma unroll
        for (int s = 1; s < NSLOTS; ++s) mx = fmaxf(mx, p[s]);
        float sum = 0.0f;
        #pragma unroll
        for (int s = 0; s < NSLOTS; ++s) { p[s] = __expf((p[s] - mx) * scale * 1.0f); }
        // note: scale must be applied to logits BEFORE subtracting max for exactness;
        // redo properly below
        (void)sum;
    }
    // proper softmax (recompute cleanly to avoid ordering bugs)
    #pragma unroll
    for (int s = 0; s < NSLOTS; ++s) p[s] = skrow[s] * qk;
    #pragma unroll
    for (int off = 1; off < 64; off <<= 1) {
        #pragma unroll
        for (int s = 0; s < NSLOTS; ++s) p[s] += __shfl_xor(p[s], off);
    }
    #pragma unroll
    for (int s = 0; s < NSLOTS; ++s) p[s] *= scale;
    float r[NSLOTS];
    {
        float mx = p[0];
        #pragma unroll
        for (int s = 1; s < NSLOTS; ++s) mx = fmaxf(mx, p[s]);
        float sum = 0.0f;
        #pragma unroll
        for (int s = 0; s < NSLOTS; ++s) { r[s] = expf(p[s] - mx); sum += r[s]; }
        float inv = 1.0f / sum;
        #pragma unroll
        for (int s = 0; s < NSLOTS; ++s) r[s] *= inv;
    }

    // read[k] = sum_s r[s] * memory[s][k]
    float readk = 0.0f;
    #pragma unroll
    for (int s = 0; s < NSLOTS; ++s) readk = fmaf(r[s], mrow[s], readk);

    rbuf[lane] = readk;
    __syncthreads();

    // q_refined[k] = q_init[k] + qr_b[k] + sum_j qr_w[k][j]*read[j]
    float qref = qk + qr_b[lane];
    #pragma unroll 4
    for (int j = 0; j < HD; ++j) qref = fmaf(rbuf[j], qr_wT[j * HD + lane], qref);

    // ---- Stage 2 ----
    float p2[NSLOTS];
    #pragma unroll
    for (int s = 0; s < NSLOTS; ++s) p2[s] = mrow[s] * qref;
    #pragma unroll
    for (int off = 1; off < 64; off <<= 1) {
        #pragma unroll
        for (int s = 0; s < NSLOTS; ++s) p2[s] += __shfl_xor(p2[s], off);
    }
    #pragma unroll
    for (int s = 0; s < NSLOTS; ++s) p2[s] *= scale;
    float a[NSLOTS];
    {
        float mx = p2[0];
        #pragma unroll
        for (int s = 1; s < NSLOTS; ++s) mx = fmaxf(mx, p2[s]);
        float sum = 0.0f;
        #pragma unroll
        for (int s = 0; s < NSLOTS; ++s) { a[s] = expf(p2[s] - mx); sum += a[s]; }
        float inv = 1.0f / sum;
        #pragma unroll
        for (int s = 0; s < NSLOTS; ++s) a[s] *= inv;
    }

    float pooledk = 0.0f;
    #pragma unroll
    for (int s = 0; s < NSLOTS; ++s) pooledk = fmaf(a[s], mrow[s], pooledk);

    __syncthreads();
    rbuf[lane] = pooledk;
    __syncthreads();

    // out[b][v] = out_b[v] + sum_k pooled[k]*out_w[v][k]
    float acc = out_b[lane];
    #pragma unroll 4
    for (int k = 0; k < HD; ++k) acc = fmaf(rbuf[k], out_wT[k * HD + lane], acc);

    out[(size_t)b * HD + lane] = acc;
}

extern "C" void kernel_launch(void* const* d_in, const int* in_sizes, int n_in,
                              void* d_out, int out_size, void* d_ws, size_t ws_size,
                              hipStream_t stream) {
    const int*   seq    = (const int*)  d_in[0];
    const float* embed  = (const float*)d_in[1];
    const float* w1     = (const float*)d_in[2];
    const float* b1     = (const float*)d_in[3];
    const float* w2     = (const float*)d_in[4];
    const float* b2     = (const float*)d_in[5];
    const float* gamma  = (const float*)d_in[6];
    const float* beta   = (const float*)d_in[7];
    const float* gate_w = (const float*)d_in[8];
    const float* gate_b = (const float*)d_in[9];
    const float* qi_w   = (const float*)d_in[10];
    const float* qi_b   = (const float*)d_in[11];
    const float* sk_w   = (const float*)d_in[12];
    const float* sk_b   = (const float*)d_in[13];
    const float* qr_w   = (const float*)d_in[14];
    const float* qr_b   = (const float*)d_in[15];
    const float* out_w  = (const float*)d_in[16];
    const float* out_b  = (const float*)d_in[17];

    float* ws = (float*)d_ws;
    float* h_table  = ws;            // 4096
    float* qi_table = ws + 4096;     // 4096
    float* sk_table = ws + 8192;     // 4096
    float* qr_wT    = ws + 12288;    // 4096
    float* out_wT   = ws + 16384;    // 4096
    float* score    = ws + 20480;    // 64
    int*   order    = (int*)(ws + 20544); // 64

    hipLaunchKernelGGL(build_tables_kernel, dim3(66), dim3(128), 0, stream,
                       embed, w1, b1, w2, b2, gamma, beta, gate_w, gate_b,
                       qi_w, qi_b, sk_w, sk_b, qr_w, out_w,
                       h_table, qi_table, sk_table, qr_wT, out_wT, score);

    hipLaunchKernelGGL(sort_tokens_kernel, dim3(1), dim3(64), 0, stream, score, order);

    hipLaunchKernelGGL(main_kernel, dim3(NBATCH), dim3(64), 0, stream,
                       seq, h_table, qi_table, sk_table, qr_wT, qr_b, out_wT, out_b,
                       order, (float*)d_out);
}

// Round 2
// 22.875 us; speedup vs baseline: 1.2266x; 1.2266x over previous
//
#include <hip/hip_runtime.h>
#include <hip/hip_bf16.h>

#define HD 64
#define LSEQ 2048
#define NBATCH 1024
#define NSLOTS 8

// ---------------- Kernel 1: per-token tables ----------------
// 64 blocks, one per vocab token v: h_table[v], qi_table[v], sk_table[v], score[v]
__global__ __launch_bounds__(128) void build_tables_kernel(
    const float* __restrict__ embed, const float* __restrict__ w1, const float* __restrict__ b1,
    const float* __restrict__ w2, const float* __restrict__ b2,
    const float* __restrict__ gamma, const float* __restrict__ beta,
    const float* __restrict__ gate_w, const float* __restrict__ gate_b,
    const float* __restrict__ qi_w, const float* __restrict__ qi_b,
    const float* __restrict__ sk_w, const float* __restrict__ sk_b,
    float* __restrict__ h_table, float* __restrict__ qi_table, float* __restrict__ sk_table,
    float* __restrict__ score)
{
    const int v = blockIdx.x;
    const int tid = threadIdx.x;

    __shared__ __align__(16) float E[HD];
    __shared__ __align__(16) float T1[2 * HD];
    __shared__ __align__(16) float Hrow[HD];

    if (tid < HD) E[tid] = embed[v * HD + tid];
    __syncthreads();

    // t1[j] = relu(b1[j] + w1[j,:].E), j = tid in [0,128)
    {
        const float4* w1r = (const float4*)(w1 + tid * HD);
        const float4* E4  = (const float4*)E;
        float t = b1[tid];
        #pragma unroll
        for (int k = 0; k < HD / 4; ++k) {
            float4 a = w1r[k], e = E4[k];
            t = fmaf(a.x, e.x, t); t = fmaf(a.y, e.y, t);
            t = fmaf(a.z, e.z, t); t = fmaf(a.w, e.w, t);
        }
        T1[tid] = fmaxf(t, 0.0f);
    }
    __syncthreads();

    // x[i] = E[i] + b2[i] + w2[i,:].T1 ; LayerNorm over i (wave 0)
    if (tid < HD) {
        const float4* w2r = (const float4*)(w2 + tid * 2 * HD);
        const float4* T4  = (const float4*)T1;
        float x = E[tid] + b2[tid];
        #pragma unroll
        for (int j = 0; j < 2 * HD / 4; ++j) {
            float4 a = w2r[j], t = T4[j];
            x = fmaf(a.x, t.x, x); x = fmaf(a.y, t.y, x);
            x = fmaf(a.z, t.z, x); x = fmaf(a.w, t.w, x);
        }
        float mu = x;
        #pragma unroll
        for (int off = 1; off < 64; off <<= 1) mu += __shfl_xor(mu, off);
        mu *= (1.0f / 64.0f);
        float d = x - mu;
        float var = d * d;
        #pragma unroll
        for (int off = 1; off < 64; off <<= 1) var += __shfl_xor(var, off);
        var *= (1.0f / 64.0f);
        float h = d * rsqrtf(var + 1e-5f) * gamma[tid] + beta[tid];
        Hrow[tid] = h;
        h_table[v * HD + tid] = h;

        float sc = h * gate_w[tid];
        #pragma unroll
        for (int off = 1; off < 64; off <<= 1) sc += __shfl_xor(sc, off);
        if (tid == 0) score[v] = sc + gate_b[0];
    }
    __syncthreads();

    // qi row (wave 0) and sk row (wave 1)
    {
        const int i = tid & 63;
        const float* W  = (tid < HD) ? qi_w : sk_w;
        const float* Bv = (tid < HD) ? qi_b : sk_b;
        const float4* Wr = (const float4*)(W + i * HD);
        const float4* H4 = (const float4*)Hrow;
        float acc = Bv[i];
        #pragma unroll
        for (int k = 0; k < HD / 4; ++k) {
            float4 a = Wr[k], h = H4[k];
            acc = fmaf(a.x, h.x, acc); acc = fmaf(a.y, h.y, acc);
            acc = fmaf(a.z, h.z, acc); acc = fmaf(a.w, h.w, acc);
        }
        float* dst = (tid < HD) ? qi_table : sk_table;
        dst[v * HD + i] = acc;
    }
}

// ---------------- Kernel 2: per-batch-row main (256 threads) ----------------
__global__ __launch_bounds__(256) void main_kernel(
    const int* __restrict__ seq,
    const float* __restrict__ h_table, const float* __restrict__ qi_table,
    const float* __restrict__ sk_table,
    const float* __restrict__ qr_w, const float* __restrict__ qr_b,
    const float* __restrict__ out_w, const float* __restrict__ out_b,
    const float* __restrict__ score,
    float* __restrict__ out)
{
    const int b    = blockIdx.x;
    const int tid  = threadIdx.x;   // 0..255
    const int w    = tid >> 6;      // wave 0..3
    const int lane = tid & 63;

    __shared__ int   hist[4][65];   // +65 stride: per-wave bank rotation
    __shared__ int   slot_tok[NSLOTS];
    __shared__ float sbuf[64];
    __shared__ int   order_s[64];
    __shared__ int   cntb[64];
    __shared__ int   last_s;
    __shared__ __align__(16) float rbuf[64];

    hist[w][lane] = 0;
    if (tid < 64) sbuf[tid] = score[tid];

    // coalesced seq load: 512 int4 per row, 2 per thread
    const int4* srow4 = (const int4*)(seq + (size_t)b * LSEQ);
    int4 a0 = srow4[tid];
    int4 a1 = srow4[256 + tid];
    if (tid == 255) last_s = a1.w;
    __syncthreads();

    atomicAdd(&hist[w][a0.x], 1); atomicAdd(&hist[w][a0.y], 1);
    atomicAdd(&hist[w][a0.z], 1); atomicAdd(&hist[w][a0.w], 1);
    atomicAdd(&hist[w][a1.x], 1); atomicAdd(&hist[w][a1.y], 1);
    atomicAdd(&hist[w][a1.z], 1); atomicAdd(&hist[w][a1.w], 1);
    __syncthreads();

    // totals + rank by (score desc, token asc)
    if (tid < 64) {
        int cnt = hist[0][tid] + hist[1][tid] + hist[2][tid] + hist[3][tid];
        float st = sbuf[tid];
        int rank = 0;
        for (int u = 0; u < 64; ++u) {
            float su = sbuf[u];
            if (su > st || (su == st && u < tid)) ++rank;
        }
        order_s[rank] = tid;
        hist[0][tid] = cnt;
    }
    __syncthreads();

    if (tid < 64) cntb[tid] = hist[0][order_s[tid]];
    __syncthreads();

    // parallel slot fill: lane r covers slots [cum_r, cum_r+cnt_r)
    if (tid < 64) {
        int cum = 0;
        for (int u = 0; u < tid; ++u) cum += cntb[u];
        int cnt = cntb[tid];
        int tok = order_s[tid];
        #pragma unroll
        for (int s = 0; s < NSLOTS; ++s)
            if (s >= cum && s < cum + cnt) slot_tok[s] = tok;
    }
    __syncthreads();

    // ---- attention on wave 0 ----
    float qk = 0.0f;
    float mrow[NSLOTS];
    const float scale = 0.125f; // 1/sqrt(64)

    if (tid < 64) {
        int st_[NSLOTS];
        #pragma unroll
        for (int s = 0; s < NSLOTS; ++s) st_[s] = slot_tok[s];

        qk = qi_table[last_s * HD + lane];

        float skrow[NSLOTS];
        #pragma unroll
        for (int s = 0; s < NSLOTS; ++s) {
            mrow[s]  = h_table[st_[s] * HD + lane];
            skrow[s] = sk_table[st_[s] * HD + lane];
        }

        // Stage 1: r = softmax(slot_keys . q_init * scale)
        float p[NSLOTS];
        #pragma unroll
        for (int s = 0; s < NSLOTS; ++s) p[s] = skrow[s] * qk;
        #pragma unroll
        for (int off = 1; off < 64; off <<= 1) {
            #pragma unroll
            for (int s = 0; s < NSLOTS; ++s) p[s] += __shfl_xor(p[s], off);
        }
        #pragma unroll
        for (int s = 0; s < NSLOTS; ++s) p[s] *= scale;
        float mx = p[0];
        #pragma unroll
        for (int s = 1; s < NSLOTS; ++s) mx = fmaxf(mx, p[s]);
        float sum = 0.0f, r[NSLOTS];
        #pragma unroll
        for (int s = 0; s < NSLOTS; ++s) { r[s] = expf(p[s] - mx); sum += r[s]; }
        float inv = 1.0f / sum;
        float readk = 0.0f;
        #pragma unroll
        for (int s = 0; s < NSLOTS; ++s) readk = fmaf(r[s] * inv, mrow[s], readk);
        rbuf[lane] = readk;
    }
    __syncthreads();

    float qref = 0.0f;
    if (tid < 64) {
        // q_refined = q_init + qr_b + qr_w . read   (row-major, float4)
        qref = qk + qr_b[lane];
        const float4* wr = (const float4*)(qr_w + lane * HD);
        const float4* r4 = (const float4*)rbuf;
        #pragma unroll
        for (int j = 0; j < HD / 4; ++j) {
            float4 a = wr[j], rv = r4[j];
            qref = fmaf(a.x, rv.x, qref); qref = fmaf(a.y, rv.y, qref);
            qref = fmaf(a.z, rv.z, qref); qref = fmaf(a.w, rv.w, qref);
        }

        // Stage 2
        float p2[NSLOTS];
        #pragma unroll
        for (int s = 0; s < NSLOTS; ++s) p2[s] = mrow[s] * qref;
        #pragma unroll
        for (int off = 1; off < 64; off <<= 1) {
            #pragma unroll
            for (int s = 0; s < NSLOTS; ++s) p2[s] += __shfl_xor(p2[s], off);
        }
        #pragma unroll
        for (int s = 0; s < NSLOTS; ++s) p2[s] *= scale;
        float mx = p2[0];
        #pragma unroll
        for (int s = 1; s < NSLOTS; ++s) mx = fmaxf(mx, p2[s]);
        float sum = 0.0f, a[NSLOTS];
        #pragma unroll
        for (int s = 0; s < NSLOTS; ++s) { a[s] = expf(p2[s] - mx); sum += a[s]; }
        float inv = 1.0f / sum;
        float pooled = 0.0f;
        #pragma unroll
        for (int s = 0; s < NSLOTS; ++s) pooled = fmaf(a[s] * inv, mrow[s], pooled);
        rbuf[lane] = pooled;
    }
    __syncthreads();

    if (tid < 64) {
        // out[b][v] = out_b[v] + out_w[v,:] . pooled   (row-major, float4)
        float acc = out_b[lane];
        const float4* wr = (const float4*)(out_w + lane * HD);
        const float4* r4 = (const float4*)rbuf;
        #pragma unroll
        for (int k = 0; k < HD / 4; ++k) {
            float4 a = wr[k], rv = r4[k];
            acc = fmaf(a.x, rv.x, acc); acc = fmaf(a.y, rv.y, acc);
            acc = fmaf(a.z, rv.z, acc); acc = fmaf(a.w, rv.w, acc);
        }
        out[(size_t)b * HD + lane] = acc;
    }
}

extern "C" void kernel_launch(void* const* d_in, const int* in_sizes, int n_in,
                              void* d_out, int out_size, void* d_ws, size_t ws_size,
                              hipStream_t stream) {
    const int*   seq    = (const int*)  d_in[0];
    const float* embed  = (const float*)d_in[1];
    const float* w1     = (const float*)d_in[2];
    const float* b1     = (const float*)d_in[3];
    const float* w2     = (const float*)d_in[4];
    const float* b2     = (const float*)d_in[5];
    const float* gamma  = (const float*)d_in[6];
    const float* beta   = (const float*)d_in[7];
    const float* gate_w = (const float*)d_in[8];
    const float* gate_b = (const float*)d_in[9];
    const float* qi_w   = (const float*)d_in[10];
    const float* qi_b   = (const float*)d_in[11];
    const float* sk_w   = (const float*)d_in[12];
    const float* sk_b   = (const float*)d_in[13];
    const float* qr_w   = (const float*)d_in[14];
    const float* qr_b   = (const float*)d_in[15];
    const float* out_w  = (const float*)d_in[16];
    const float* out_b  = (const float*)d_in[17];

    float* ws = (float*)d_ws;
    float* h_table  = ws;            // 4096
    float* qi_table = ws + 4096;     // 4096
    float* sk_table = ws + 8192;     // 4096
    float* score    = ws + 12288;    // 64

    hipLaunchKernelGGL(build_tables_kernel, dim3(64), dim3(128), 0, stream,
                       embed, w1, b1, w2, b2, gamma, beta, gate_w, gate_b,
                       qi_w, qi_b, sk_w, sk_b,
                       h_table, qi_table, sk_table, score);

    hipLaunchKernelGGL(main_kernel, dim3(NBATCH), dim3(256), 0, stream,
                       seq, h_table, qi_table, sk_table,
                       qr_w, qr_b, out_w, out_b, score, (float*)d_out);
}